// Round 14
// baseline (291.559 us; speedup 1.0000x reference)
//
#include <hip/hip_runtime.h>

// Problem constants
#define BB 8
#define EE 16
#define NN 262144          // H*W = 512*512
#define KK 32
#define DELTA_VAR 0.5f
#define TWO_DELTA_DIST 3.0f
#define GAMMA_REG 0.001f

#define P1 2048            // pixels per block, kernel 1
#define NBX1 (NN / P1)     // 128
#define P3 1024            // pixels per block, kernel 3
#define NBX3 (NN / P3)     // 256
#define COLS 544           // 512 e*32+k sums + 32 counts

#define SCALE_S 262144.0f  // 2^18 fixed-point scale for embedding sums
#define SCALE_V 1024.0f    // 2^10 fixed-point scale for hinged^2 sums
#define INV_SS (1.0 / 262144.0)
#define INV_SV (1.0 / 1024.0)

// ws layout (bytes) -- every byte written before read, NO memset needed:
//   P_part : int  [BB][NBX1][COLS] @ 0        (2,228,224 B)  plain stores
//   v_part : uint [BB][NBX3][KK]   @ 2228224  (262,144 B)    plain stores
//   g_sumf : f32  [BB][512]        @ 2490368  (16,384 B)
//   g_cntf : f32  [BB][KK]         @ 2506752  (1,024 B)

// ---------------------------------------------------------------------------
// Kernel 1: per-(b,k) counts and per-(b,k,e) quantized sums. LDS int atomics
// (native ds_add, fire-and-forget) -> UNIQUE per-block slot flush with plain
// coalesced stores. ZERO global atomics (R13 showed the 544 contended
// device-scope atomics/block generated 16B HBM traffic each = the stall).
// ---------------------------------------------------------------------------
__global__ __launch_bounds__(256) void k1_sums(const float* __restrict__ emb,
                                               const int* __restrict__ mask,
                                               int* __restrict__ P_part) {
    __shared__ int hist[EE * 33];       // pad 33: bank (e+k)%32
    __shared__ unsigned int chist[KK];
    const int t = threadIdx.x;
    const int bx = blockIdx.x, b = blockIdx.y;

    for (int i = t; i < EE * 33; i += 256) hist[i] = 0;
    if (t < KK) chist[t] = 0u;
    __syncthreads();

    const float4* ef = (const float4*)(emb + (size_t)b * EE * NN);
    const int4*   mp = (const int4*)(mask + (size_t)b * NN);
    const int f0 = bx * (P1 / 4);

    #pragma unroll
    for (int r = 0; r < P1 / 1024; r++) {
        const int fidx = f0 + r * 256 + t;
        // 16 independent coalesced float4 streams (MLP) + labels
        float4 x[EE];
        #pragma unroll
        for (int e = 0; e < EE; e++) x[e] = ef[(size_t)e * (NN / 4) + fidx];
        int4 l4 = mp[fidx];
        int ks[4] = {l4.x, l4.y, l4.z, l4.w};

        #pragma unroll
        for (int j = 0; j < 4; j++) {
            int k = ks[j];
            if (k > 0) {
                int kk = k - 1;
                atomicAdd(&chist[kk], 1u);
                #pragma unroll
                for (int e = 0; e < EE; e++) {
                    float xv = (j == 0) ? x[e].x : (j == 1) ? x[e].y
                             : (j == 2) ? x[e].z : x[e].w;
                    atomicAdd(&hist[e * 33 + kk], (int)rintf(xv * SCALE_S));
                }
            }
        }
    }
    __syncthreads();

    // flush: unique slot, plain coalesced stores, no atomics
    int* row = P_part + ((size_t)b * NBX1 + bx) * COLS;
    for (int c = t; c < COLS; c += 256) {
        int v = (c < 512) ? hist[(c >> 5) * 33 + (c & 31)] : (int)chist[c - 512];
        row[c] = v;
    }
}

// ---------------------------------------------------------------------------
// Kernel 2: reduce the 128 block-partials per batch (i64 exact), write
// float sums (/SCALE_S) + float counts. Grid (9 col-groups, 8 b).
// ---------------------------------------------------------------------------
__global__ __launch_bounds__(256) void k2_reduce(const int* __restrict__ P_part,
                                                 float* __restrict__ g_sumf,
                                                 float* __restrict__ g_cntf) {
    __shared__ long long part[4][64];
    const int t = threadIdx.x;
    const int g = blockIdx.x, b = blockIdx.y;
    const int cl = t & 63, rc = t >> 6;      // col-in-group, row-chunk (4x32)
    const int col = g * 64 + cl;

    long long acc = 0;
    if (col < COLS) {
        const int* base = P_part + (size_t)b * NBX1 * COLS + col;
        #pragma unroll 8
        for (int r = rc * (NBX1 / 4); r < (rc + 1) * (NBX1 / 4); r++)
            acc += base[(size_t)r * COLS];
    }
    part[rc][cl] = acc;
    __syncthreads();
    if (t < 64 && col < COLS) {
        long long s = part[0][cl] + part[1][cl] + part[2][cl] + part[3][cl];
        if (col < 512) g_sumf[b * 512 + col] = (float)((double)s * INV_SS);
        else           g_cntf[b * KK + (col - 512)] = (float)s;
    }
}

// ---------------------------------------------------------------------------
// Kernel 3: variance term. Prologue computes centers from g_sumf/g_cntf
// (x17 LDS padding: 17k mod 32 bijective -> conflict-free label reads).
// u32 LDS hist -> unique-slot plain-store flush. No atomics to global.
// ---------------------------------------------------------------------------
__global__ __launch_bounds__(256) void k3_var(const float* __restrict__ emb,
                                              const int* __restrict__ mask,
                                              const float* __restrict__ g_sumf,
                                              const float* __restrict__ g_cntf,
                                              unsigned int* __restrict__ v_part) {
    __shared__ float c_lds[KK * 17];
    __shared__ unsigned int vhist[KK];
    const int t = threadIdx.x;
    const int bx = blockIdx.x, b = blockIdx.y;

    for (int idx = t; idx < 512; idx += 256) {
        int e = idx >> 5, k = idx & 31;
        float cnt = g_cntf[b * KK + k];
        c_lds[k * 17 + e] = g_sumf[b * 512 + idx] / fmaxf(cnt, 1.0f);
    }
    if (t < KK) vhist[t] = 0u;
    __syncthreads();

    const float4* ef = (const float4*)(emb + (size_t)b * EE * NN);
    const int fidx = bx * (P3 / 4) + t;
    float4 x[EE];
    #pragma unroll
    for (int e = 0; e < EE; e++) x[e] = ef[(size_t)e * (NN / 4) + fidx];
    int4 l4 = ((const int4*)(mask + (size_t)b * NN))[fidx];
    int ks[4] = {l4.x, l4.y, l4.z, l4.w};

    #pragma unroll
    for (int j = 0; j < 4; j++) {
        int k = ks[j];
        if (k > 0) {
            const float* c = &c_lds[(k - 1) * 17];
            float sq = 0.0f;
            #pragma unroll
            for (int e = 0; e < EE; e++) {
                float xv = (j == 0) ? x[e].x : (j == 1) ? x[e].y
                         : (j == 2) ? x[e].z : x[e].w;
                float d = xv - c[e];
                sq += d * d;
            }
            float dd = sqrtf(sq);
            float h = fmaxf(dd - DELTA_VAR, 0.0f);
            atomicAdd(&vhist[k - 1], (unsigned int)rintf(h * h * SCALE_V));
        }
    }
    __syncthreads();

    if (t < KK) v_part[((size_t)b * NBX3 + bx) * KK + t] = vhist[t];
}

// ---------------------------------------------------------------------------
// Kernel 4: finalize. One block; thread (b = t>>5, k = t&31). Prologue
// reduces the 256 v-partials per (b,k) in u64 registers (exact).
// ---------------------------------------------------------------------------
__global__ __launch_bounds__(256) void k4_final(const float* __restrict__ g_sumf,
                                                const float* __restrict__ g_cntf,
                                                const unsigned int* __restrict__ v_part,
                                                float* __restrict__ out) {
    __shared__ float cen[BB][KK][EE];
    __shared__ float pres[BB][KK];
    __shared__ float red[BB][4];
    const int t = threadIdx.x;
    const int b = t >> 5, k = t & 31;

    unsigned long long vacc = 0ull;
    const unsigned int* vp = v_part + (size_t)b * NBX3 * KK + k;
    #pragma unroll 8
    for (int r = 0; r < NBX3; r++) vacc += vp[(size_t)r * KK];

    float cnt = g_cntf[b * KK + k];
    float sc = fmaxf(cnt, 1.0f);
    float c2 = 0.0f;
    #pragma unroll
    for (int e = 0; e < EE; e++) {
        float c = g_sumf[b * 512 + e * 32 + k] / sc;
        cen[b][k][e] = c;
        c2 += c * c;
    }
    float presf = (cnt > 0.0f) ? 1.0f : 0.0f;
    pres[b][k] = presf;
    float per_inst = (float)((double)vacc * INV_SV) / sc;
    float cn = presf * sqrtf(c2);
    __syncthreads();

    float hp = 0.0f;
    if (presf > 0.0f) {
        for (int j = k + 1; j < KK; j++) {
            if (pres[b][j] > 0.0f) {
                float dsq = 0.0f;
                #pragma unroll
                for (int e = 0; e < EE; e++) {
                    float d = cen[b][k][e] - cen[b][j][e];
                    dsq += d * d;
                }
                float dd = sqrtf(dsq);
                float h = fmaxf(TWO_DELTA_DIST - dd, 0.0f);
                hp += h * h;
            }
        }
    }

    // width-32 subgroups align with the b = t>>5 partition on wave64
    float v0 = per_inst, v1 = hp, v2 = cn, v3 = presf;
    #pragma unroll
    for (int off = 16; off > 0; off >>= 1) {
        v0 += __shfl_down(v0, off, 32);
        v1 += __shfl_down(v1, off, 32);
        v2 += __shfl_down(v2, off, 32);
        v3 += __shfl_down(v3, off, 32);
    }
    if (k == 0) {
        float n_inst = v3;
        float validf = (n_inst > 0.0f) ? 1.0f : 0.0f;
        float safe_n = fmaxf(n_inst, 1.0f);
        float lv = v0 / safe_n;
        float npairs = n_inst * (n_inst - 1.0f) * 0.5f;
        float ld = v1 / fmaxf(npairs, 1.0f);
        float lr = v2 / safe_n;
        red[b][0] = lv * validf;
        red[b][1] = ld * validf;
        red[b][2] = lr * validf;
        red[b][3] = validf;
    }
    __syncthreads();
    if (t == 0) {
        float sv = 0, sd = 0, sr = 0, vb = 0;
        for (int b2 = 0; b2 < BB; b2++) {
            sv += red[b2][0]; sd += red[b2][1]; sr += red[b2][2]; vb += red[b2][3];
        }
        vb = fmaxf(vb, 1.0f);
        float L_var = sv / vb, L_dist = sd / vb, L_reg = sr / vb;
        out[0] = L_var + L_dist + GAMMA_REG * L_reg;
        out[1] = L_var;
        out[2] = L_dist;
        out[3] = L_reg;
    }
}

extern "C" void kernel_launch(void* const* d_in, const int* in_sizes, int n_in,
                              void* d_out, int out_size, void* d_ws, size_t ws_size,
                              hipStream_t stream) {
    const float* emb  = (const float*)d_in[0];
    const int*   mask = (const int*)d_in[1];
    float* out = (float*)d_out;
    char* ws = (char*)d_ws;

    int*          P_part = (int*)(ws);                      // 2,228,224 B
    unsigned int* v_part = (unsigned int*)(ws + 2228224);   //   262,144 B
    float*        g_sumf = (float*)(ws + 2490368);          //    16,384 B
    float*        g_cntf = (float*)(ws + 2506752);          //     1,024 B

    dim3 blk(256);
    k1_sums <<<dim3(NBX1, BB), blk, 0, stream>>>(emb, mask, P_part);
    k2_reduce<<<dim3(9,    BB), blk, 0, stream>>>(P_part, g_sumf, g_cntf);
    k3_var  <<<dim3(NBX3, BB), blk, 0, stream>>>(emb, mask, g_sumf, g_cntf, v_part);
    k4_final<<<dim3(1),        blk, 0, stream>>>(g_sumf, g_cntf, v_part, out);
}